// Round 5
// baseline (586.904 us; speedup 1.0000x reference)
//
#include <hip/hip_runtime.h>
#include <stdint.h>

// ---------------- types ----------------
typedef short bf16x8 __attribute__((ext_vector_type(8)));          // 8 bf16 in 4 VGPRs (MFMA A/B frag)
typedef float f32x4 __attribute__((ext_vector_type(4)));           // MFMA C/D frag
typedef unsigned short u16x8 __attribute__((ext_vector_type(8)));  // 16B bf16 chunk

#define N_NODES 50000
#define DIM 512                  // h width
#define KDIM 1024                // GEMM K ([h|agg])
#define NPAD 50048               // 391 * 128
#define M_TILES 391
#define GEMM_GRID 1568           // 8 XCDs * 196 slots (1 guard block at x=7)
#define FLAT_TOTAL 25600000ULL   // N_NODES * DIM
#define NBLK_FC 2048

__device__ __forceinline__ unsigned short f2bf(float f) {
    unsigned u = __float_as_uint(f);
    unsigned r = u + 0x7FFFu + ((u >> 16) & 1u);   // RNE
    return (unsigned short)(r >> 16);
}
__device__ __forceinline__ float bf2f(unsigned short h) {
    return __uint_as_float(((unsigned)h) << 16);
}

// async global -> LDS, 16B per lane; per-lane global addr, wave-uniform LDS base + lane*16.
__device__ __forceinline__ void llds16(const void* g, void* l) {
    __builtin_amdgcn_global_load_lds(
        (const __attribute__((address_space(1))) void*)g,
        (__attribute__((address_space(3))) void*)l,
        16, 0, 0);
}

// ---------------- cast x: fp32 [50000,512] -> bf16 ----------------
__global__ void cast_x(const float* __restrict__ x, unsigned short* __restrict__ o) {
    size_t i = ((size_t)blockIdx.x * blockDim.x + threadIdx.x) * 8;  // 12500*256*8 = 25.6M exactly
    float4 v0 = *(const float4*)&x[i];
    float4 v1 = *(const float4*)&x[i + 4];
    u16x8 r;
    r[0] = f2bf(v0.x); r[1] = f2bf(v0.y); r[2] = f2bf(v0.z); r[3] = f2bf(v0.w);
    r[4] = f2bf(v1.x); r[5] = f2bf(v1.y); r[6] = f2bf(v1.z); r[7] = f2bf(v1.w);
    *(u16x8*)&o[i] = r;
}

// ---------------- cast both W [512,1024] fp32 -> bf16 (straight; B of NT-GEMM is W itself) ----
__global__ void cast_w2(const float* __restrict__ w1, const float* __restrict__ w2,
                        unsigned short* __restrict__ o1, unsigned short* __restrict__ o2) {
    int b = blockIdx.x;
    const float* w = (b < 256) ? w1 : w2;
    unsigned short* o = (b < 256) ? o1 : o2;
    int idx = ((b & 255) * 256 + threadIdx.x) * 8;     // 524288 elems per matrix
    float4 v0 = *(const float4*)&w[idx];
    float4 v1 = *(const float4*)&w[idx + 4];
    u16x8 r;
    r[0] = f2bf(v0.x); r[1] = f2bf(v0.y); r[2] = f2bf(v0.z); r[3] = f2bf(v0.w);
    r[4] = f2bf(v1.x); r[5] = f2bf(v1.y); r[6] = f2bf(v1.z); r[7] = f2bf(v1.w);
    *(u16x8*)&o[idx] = r;
}

// ---------------- agg: G[i] = 0.5*(H[n0]+H[n1]), bf16 [N,512] (gather on 51MB L3-resident) ----
__global__ void agg_mean(const unsigned short* __restrict__ H, const int* __restrict__ nb,
                         unsigned short* __restrict__ G) {
    int t = threadIdx.x;
    int i = blockIdx.x * 4 + (t >> 6);          // 12500 * 4 = 50000 rows exactly
    int lane = t & 63;
    int c = lane * 8;
    int n0 = nb[i * 2], n1 = nb[i * 2 + 1];
    u16x8 a = *(const u16x8*)&H[(size_t)n0 * DIM + c];
    u16x8 b = *(const u16x8*)&H[(size_t)n1 * DIM + c];
    u16x8 o;
#pragma unroll
    for (int j = 0; j < 8; j++) o[j] = f2bf((bf2f(a[j]) + bf2f(b[j])) * 0.5f);
    *(u16x8*)&G[(size_t)i * DIM + c] = o;
}

// ---------------- GEMM: C[M,512] = relu( [A1|A2][M,1024] * W[512,1024]^T ) ----------------
// A never materialized as a concat: staging switches base pointer at k=512.
// OUT_MODE 0: bf16 store, no row guard. OUT_MODE 1: fp32 store, guard row < N_NODES.
// XCD-affinity swizzle: all bn-blocks of one bm land on one XCD -> A-tile L2-local.
template <int OUT_MODE>
__global__ __launch_bounds__(256)
void gemm_fused(const unsigned short* __restrict__ A1, const unsigned short* __restrict__ A2,
                const unsigned short* __restrict__ B, void* __restrict__ C) {
    __shared__ unsigned short As[2][128 * 32];   // 2 x 8 KB (k-halves of BK=64)
    __shared__ unsigned short Bs[2][128 * 32];

    int x = blockIdx.x & 7;            // XCD id (round-robin heuristic)
    int g = blockIdx.x >> 3;           // 0..195 within XCD
    int bm = x + 8 * (g >> 2);         // bm % 8 == x
    int bn = g & 3;                    // 4 N-tiles (N=512)
    if (bm >= M_TILES) return;         // 1 guard block (x=7, last group)

    int t = threadIdx.x;
    int lane = t & 63;
    int wave = t >> 6;
    int m_off = (wave >> 1) * 64;      // 2x2 waves over the 128x128 tile
    int n_off = (wave & 1) * 64;
    int lrow = lane & 15;
    int lk = (lane >> 4) * 8;

    f32x4 acc[4][4];
#pragma unroll
    for (int i = 0; i < 4; i++)
#pragma unroll
        for (int j = 0; j < 4; j++) acc[i][j] = (f32x4){0.f, 0.f, 0.f, 0.f};

    // staging: thread t covers 16B chunk (row t>>2, chunk t&3) and same +64 rows
    size_t arow = (size_t)(bm * 128 + (t >> 2)) * DIM + (t & 3) * 8;     // stride 512 (A1/A2)
    size_t brow = (size_t)(bn * 128 + (t >> 2)) * KDIM + (t & 3) * 8;    // stride 1024 (W)

    for (int k0 = 0; k0 < KDIM; k0 += 64) {    // 16 iterations; first 8 read A1, last 8 A2
        const unsigned short* pa = ((k0 < DIM) ? A1 : A2) + arow + (k0 & (DIM - 1));
        const unsigned short* pb = B + brow + k0;
        __syncthreads();                       // prev iter's ds_reads done before overwrite
        llds16(pa,                 &As[0][t * 8]);
        llds16(pa + 64 * DIM,      &As[0][t * 8 + 2048]);
        llds16(pb,                 &Bs[0][t * 8]);
        llds16(pb + 64 * KDIM,     &Bs[0][t * 8 + 2048]);
        llds16(pa + 32,            &As[1][t * 8]);
        llds16(pa + 32 + 64 * DIM, &As[1][t * 8 + 2048]);
        llds16(pb + 32,            &Bs[1][t * 8]);
        llds16(pb + 32 + 64 * KDIM,&Bs[1][t * 8 + 2048]);
        __syncthreads();                       // drains vmcnt -> LDS valid

#pragma unroll
        for (int h = 0; h < 2; h++) {
            bf16x8 af[4], bfr[4];
#pragma unroll
            for (int i = 0; i < 4; i++)
                af[i] = *(const bf16x8*)&As[h][(m_off + i * 16 + lrow) * 32 + lk];
#pragma unroll
            for (int j = 0; j < 4; j++)
                bfr[j] = *(const bf16x8*)&Bs[h][(n_off + j * 16 + lrow) * 32 + lk];
#pragma unroll
            for (int i = 0; i < 4; i++)
#pragma unroll
                for (int j = 0; j < 4; j++)
                    acc[i][j] = __builtin_amdgcn_mfma_f32_16x16x32_bf16(af[i], bfr[j], acc[i][j], 0, 0, 0);
        }
    }

    // epilogue: C/D layout col=lane&15, row=(lane>>4)*4+reg; relu fused
    int lc = lane & 15;
    int lr = (lane >> 4) << 2;
#pragma unroll
    for (int i = 0; i < 4; i++) {
        int row0 = bm * 128 + m_off + i * 16 + lr;
#pragma unroll
        for (int j = 0; j < 4; j++) {
            int col = bn * 128 + n_off + j * 16 + lc;
            f32x4 v = acc[i][j];
            if (OUT_MODE == 0) {
                unsigned short* Cb = (unsigned short*)C;
#pragma unroll
                for (int r = 0; r < 4; r++)
                    Cb[(size_t)(row0 + r) * DIM + col] = f2bf(fmaxf(v[r], 0.f));
            } else {
                float* Cf = (float*)C;
#pragma unroll
                for (int r = 0; r < 4; r++)
                    if (row0 + r < N_NODES)
                        Cf[(size_t)(row0 + r) * DIM + col] = fmaxf(v[r], 0.f);
            }
        }
    }
}

// ---------------- FC: two 25.6M dot products, per-block partials (deterministic) ----------
__global__ void fc_reduce(const float* __restrict__ flat, const float* __restrict__ fcw,
                          float2* __restrict__ partials) {
    float s0 = 0.f, s1 = 0.f;
    size_t stride = (size_t)gridDim.x * blockDim.x * 4;
    for (size_t i = ((size_t)blockIdx.x * blockDim.x + threadIdx.x) * 4; i < FLAT_TOTAL; i += stride) {
        float4 v  = *(const float4*)&flat[i];
        float4 w0 = *(const float4*)&fcw[i];
        float4 w1 = *(const float4*)&fcw[FLAT_TOTAL + i];
        s0 += v.x * w0.x + v.y * w0.y + v.z * w0.z + v.w * w0.w;
        s1 += v.x * w1.x + v.y * w1.y + v.z * w1.z + v.w * w1.w;
    }
#pragma unroll
    for (int off = 32; off > 0; off >>= 1) {
        s0 += __shfl_down(s0, off);
        s1 += __shfl_down(s1, off);
    }
    __shared__ float r0[4], r1[4];
    int lane = threadIdx.x & 63, w = threadIdx.x >> 6;
    if (lane == 0) { r0[w] = s0; r1[w] = s1; }
    __syncthreads();
    if (threadIdx.x == 0)
        partials[blockIdx.x] = make_float2(r0[0] + r0[1] + r0[2] + r0[3],
                                           r1[0] + r1[1] + r1[2] + r1[3]);
}

// ---------------- final reduce + log_softmax ----------------
__global__ void reduce_finalize(const float2* __restrict__ partials, const float* __restrict__ fcb,
                                float* __restrict__ out2) {
    float s0 = 0.f, s1 = 0.f;
    for (int k = threadIdx.x; k < NBLK_FC; k += 1024) {
        float2 pr = partials[k];
        s0 += pr.x; s1 += pr.y;
    }
#pragma unroll
    for (int off = 32; off > 0; off >>= 1) {
        s0 += __shfl_down(s0, off);
        s1 += __shfl_down(s1, off);
    }
    __shared__ float r0[16], r1[16];
    int lane = threadIdx.x & 63, w = threadIdx.x >> 6;
    if (lane == 0) { r0[w] = s0; r1[w] = s1; }
    __syncthreads();
    if (threadIdx.x == 0) {
        float l0 = fcb[0], l1 = fcb[1];
#pragma unroll
        for (int k = 0; k < 16; k++) { l0 += r0[k]; l1 += r1[k]; }
        float m = fmaxf(l0, l1);
        float lse = m + logf(expf(l0 - m) + expf(l1 - m));
        out2[0] = l0 - lse;
        out2[1] = l1 - lse;
    }
}

// ---------------- launch ----------------
extern "C" void kernel_launch(void* const* d_in, const int* in_sizes, int n_in,
                              void* d_out, int out_size, void* d_ws, size_t ws_size,
                              hipStream_t stream) {
    const float* x   = (const float*)d_in[0];
    const int*   n1  = (const int*)d_in[1];
    const int*   n2  = (const int*)d_in[2];
    const float* W1  = (const float*)d_in[3];
    const float* W2  = (const float*)d_in[4];
    const float* fcw = (const float*)d_in[5];
    const float* fcb = (const float*)d_in[6];
    float* out = (float*)d_out;

    // workspace (16B aligned). Pad rows 50000..50047 keep 0xAA poison = tiny finite bf16
    // -> harmless garbage through GEMMs; agg reads only real rows; out-store guarded.
    char* ws = (char*)d_ws;
    const size_t HB = (size_t)NPAD * DIM * 2;                    // 51,249,152 B
    unsigned short* Xb   = (unsigned short*)(ws);                // x bf16
    unsigned short* Xag  = (unsigned short*)(ws + HB);           // agg1
    unsigned short* H1   = (unsigned short*)(ws + 2 * HB);       // layer-1 out
    unsigned short* H1ag = (unsigned short*)(ws + 3 * HB);       // agg2
    unsigned short* W1b  = (unsigned short*)(ws + 4 * HB);
    unsigned short* W2b  = (unsigned short*)(ws + 4 * HB + (size_t)DIM * KDIM * 2);
    float2* partials     = (float2*)(ws + 4 * HB + 2 * (size_t)DIM * KDIM * 2);

    cast_w2<<<512, 256, 0, stream>>>(W1, W2, W1b, W2b);
    cast_x<<<12500, 256, 0, stream>>>(x, Xb);

    agg_mean<<<12500, 256, 0, stream>>>(Xb, n1, Xag);
    gemm_fused<0><<<GEMM_GRID, 256, 0, stream>>>(Xb, Xag, W1b, H1);
    agg_mean<<<12500, 256, 0, stream>>>(H1, n2, H1ag);
    gemm_fused<1><<<GEMM_GRID, 256, 0, stream>>>(H1, H1ag, W2b, out);

    fc_reduce<<<NBLK_FC, 256, 0, stream>>>(out, fcw, partials);
    reduce_finalize<<<1, 1024, 0, stream>>>(partials, fcb, out + FLAT_TOTAL);
}